// Round 7
// baseline (236.433 us; speedup 1.0000x reference)
//
#include <hip/hip_runtime.h>

// Problem constants
#define NB 2
#define LL 2048
#define DD 1024
#define HH 16
#define NHH (NB*HH)          // 32 (n,h) pairs
#define LT (LL/64)           // 32 tiles of 64
#define KT16 (LL/16)         // 128 16-col tiles
#define CEXP 0.0450842200277801f   // log2(e)/32 : exp(x/32) == exp2(x*CEXP)

typedef __bf16 bf16x8 __attribute__((ext_vector_type(8)));
typedef unsigned short u16x8 __attribute__((ext_vector_type(8)));
typedef float f32x4 __attribute__((ext_vector_type(4)));

#define MFMA16 __builtin_amdgcn_mfma_f32_16x16x32_bf16
#define EXP2 __builtin_amdgcn_exp2f
#define LOG2 __builtin_amdgcn_logf

__device__ __forceinline__ unsigned short f2bf(float f) {
    unsigned u = __float_as_uint(f);
    return (unsigned short)((u + 0x7fffu + ((u >> 16) & 1u)) >> 16);   // RNE
}
__device__ __forceinline__ float bf2f(unsigned short u) {
    return __uint_as_float(((unsigned)u) << 16);
}
__device__ __forceinline__ bf16x8 ldfrag(const unsigned short* p) {
    return *reinterpret_cast<const bf16x8*>(p);
}
__device__ __forceinline__ bf16x8 cvt8v(float4 a, float4 b) {
    u16x8 u;
    u[0]=f2bf(a.x); u[1]=f2bf(a.y); u[2]=f2bf(a.z); u[3]=f2bf(a.w);
    u[4]=f2bf(b.x); u[5]=f2bf(b.y); u[6]=f2bf(b.z); u[7]=f2bf(b.w);
    return __builtin_bit_cast(bf16x8, u);
}
__device__ __forceinline__ ushort4 pack4(f32x4 d, float sc) {
    ushort4 o;
    o.x = f2bf(d[0]*sc); o.y = f2bf(d[1]*sc); o.z = f2bf(d[2]*sc); o.w = f2bf(d[3]*sc);
    return o;
}
// async global->LDS, 16B per lane; LDS dest must be linear (base + lane*16)
__device__ __forceinline__ void gload16(const unsigned short* g, unsigned short* l) {
    __builtin_amdgcn_global_load_lds(
        (const __attribute__((address_space(1))) unsigned int*)g,
        (__attribute__((address_space(3))) unsigned int*)l, 16, 0, 0);
}

// ---------------------------------------------------------------------------
// K0 (prep): wcvt ONLY (6 blocks) -- fcw cvt moved into proj's grid (z=2),
// since proj does not depend on fcwb. One fewer full-size dispatch.
// ---------------------------------------------------------------------------
__global__ __launch_bounds__(256) void prep_kernel(
    const float* __restrict__ Wk, const float* __restrict__ Wq,
    const float* __restrict__ Wv, unsigned short* __restrict__ wfrag)
{
    const int t = threadIdx.x;
    const int s = blockIdx.x * 256 + t;   // 0..1535
    const int m = s >> 9;
    const int rem = s & 511;
    const int f = rem >> 6;
    const int lane = rem & 63;
    const int n16 = lane & 15, quad = lane >> 4;
    const int mt = f >> 1, half = f & 1;
    const float* W = (m == 0) ? Wk : (m == 1) ? Wq : Wv;
    const float* p = W + (mt*16 + n16)*64 + quad*8 + half*32;
    float4 a = *reinterpret_cast<const float4*>(p);
    float4 b = *reinterpret_cast<const float4*>(p + 4);
    *reinterpret_cast<bf16x8*>(wfrag + (size_t)s * 8) = cvt8v(a, b);
}

// ---------------------------------------------------------------------------
// K1: projections via MFMA, D = W(A) . X^T(B); grid (64,16,3).
// z=0: keys/query/okeys (Wk,Wq) + ediag; z=1: values/ovals (Wv);
// z=2: fc_w fp32 -> bf16 (folded from old prep -- no dependency on proj
// inputs, overlaps with the latency-bound projection blocks).
// ---------------------------------------------------------------------------
__global__ __launch_bounds__(256) void proj_kernel(
    const float* __restrict__ values, const float* __restrict__ keys,
    const float* __restrict__ query,  const float* __restrict__ ovals,
    const float* __restrict__ okeys,  const unsigned short* __restrict__ wfrag,
    const float* __restrict__ fc_w,   unsigned short* __restrict__ fcwb,
    unsigned short* __restrict__ qb, unsigned short* __restrict__ okb,
    unsigned short* __restrict__ vb, unsigned short* __restrict__ ovb,
    float* __restrict__ ediag)
{
    const int t = threadIdx.x;
    if (blockIdx.z == 2) {
        const int id = blockIdx.y * 64 + blockIdx.x;       // 0..1023
        const int idx = id * 1024 + t * 4;
        float4 wv = *reinterpret_cast<const float4*>(fc_w + idx);
        ushort4 o;
        o.x = f2bf(wv.x); o.y = f2bf(wv.y); o.z = f2bf(wv.z); o.w = f2bf(wv.w);
        *reinterpret_cast<ushort4*>(fcwb + idx) = o;
        return;
    }
    const int w = t >> 6;
    const int lane = t & 63;
    const int n16 = lane & 15;
    const int quad = lane >> 4;
    const int h = blockIdx.y;
    const int row = blockIdx.x * 64 + w * 16 + n16;  // (n*L+l) == this lane's C-col
    const int nn = row >> 11;
    const int ll = row & 2047;
    const size_t xoff  = (size_t)row * DD + h * 64 + quad * 8;       // B-frag src
    const size_t qbase = (((size_t)(nn * HH + h)) * LL + ll) * 64;   // [nh][l][64]
    const size_t vbase = (size_t)row * DD + h * 64;                  // [row][1024]

    if (blockIdx.z == 0) {
        // ---- issue ALL loads first (independent) ----
        const float4* kp = reinterpret_cast<const float4*>(keys  + xoff);
        const float4* qp = reinterpret_cast<const float4*>(query + xoff);
        const float4* op = reinterpret_cast<const float4*>(okeys + xoff);
        float4 k0 = kp[0], k1 = kp[1], k2 = kp[8], k3 = kp[9];   // +0,+4,+32,+36
        float4 q0 = qp[0], q1 = qp[1], q2 = qp[8], q3 = qp[9];
        float4 o0 = op[0], o1 = op[1], o2 = op[8], o3 = op[9];
        bf16x8 wk[8], wq[8];
#pragma unroll
        for (int f = 0; f < 8; ++f) {
            wk[f] = ldfrag(wfrag + (size_t)(f * 64 + lane) * 8);
            wq[f] = ldfrag(wfrag + (size_t)((8 + f) * 64 + lane) * 8);
        }
        // ---- convert ----
        bf16x8 xk0 = cvt8v(k0, k1), xk1 = cvt8v(k2, k3);
        bf16x8 xq0 = cvt8v(q0, q1), xq1 = cvt8v(q2, q3);
        bf16x8 xo0 = cvt8v(o0, o1), xo1 = cvt8v(o2, o3);
        // ---- MFMA ----
        f32x4 ka[4], qa[4];
#pragma unroll
        for (int mt = 0; mt < 4; ++mt) {
            f32x4 d = {0.f,0.f,0.f,0.f};
            d = MFMA16(wk[mt*2], xk0, d, 0,0,0);
            ka[mt] = MFMA16(wk[mt*2+1], xk1, d, 0,0,0);
        }
#pragma unroll
        for (int mt = 0; mt < 4; ++mt) {
            f32x4 d = {0.f,0.f,0.f,0.f};
            d = MFMA16(wq[mt*2], xq0, d, 0,0,0);
            qa[mt] = MFMA16(wq[mt*2+1], xq1, d, 0,0,0);
            *reinterpret_cast<ushort4*>(qb + qbase + mt*16 + quad*4) = pack4(qa[mt], CEXP);
        }
#pragma unroll
        for (int mt = 0; mt < 4; ++mt) {
            f32x4 d = {0.f,0.f,0.f,0.f};
            d = MFMA16(wk[mt*2], xo0, d, 0,0,0);
            d = MFMA16(wk[mt*2+1], xo1, d, 0,0,0);
            *reinterpret_cast<ushort4*>(okb + qbase + mt*16 + quad*4) = pack4(d, 1.0f);
        }
        // ediag[l] = sum_d q*k (fp32)
        float p = 0.f;
#pragma unroll
        for (int mt = 0; mt < 4; ++mt)
            p += qa[mt][0]*ka[mt][0] + qa[mt][1]*ka[mt][1]
               + qa[mt][2]*ka[mt][2] + qa[mt][3]*ka[mt][3];
        p += __shfl_xor(p, 16);
        p += __shfl_xor(p, 32);
        if (lane < 16)
            ediag[((size_t)(nn * HH + h)) * LL + ll] = p;
    } else {
        const float4* vp = reinterpret_cast<const float4*>(values + xoff);
        const float4* op = reinterpret_cast<const float4*>(ovals  + xoff);
        float4 v0 = vp[0], v1 = vp[1], v2 = vp[8], v3 = vp[9];
        float4 o0 = op[0], o1 = op[1], o2 = op[8], o3 = op[9];
        bf16x8 wv[8];
#pragma unroll
        for (int f = 0; f < 8; ++f)
            wv[f] = ldfrag(wfrag + (size_t)((16 + f) * 64 + lane) * 8);
        bf16x8 xv0 = cvt8v(v0, v1), xv1 = cvt8v(v2, v3);
        bf16x8 xo0 = cvt8v(o0, o1), xo1 = cvt8v(o2, o3);
#pragma unroll
        for (int mt = 0; mt < 4; ++mt) {
            f32x4 d = {0.f,0.f,0.f,0.f};
            d = MFMA16(wv[mt*2], xv0, d, 0,0,0);
            d = MFMA16(wv[mt*2+1], xv1, d, 0,0,0);
            *reinterpret_cast<ushort4*>(vb + vbase + mt*16 + quad*4) = pack4(d, 1.0f);
        }
#pragma unroll
        for (int mt = 0; mt < 4; ++mt) {
            f32x4 d = {0.f,0.f,0.f,0.f};
            d = MFMA16(wv[mt*2], xo0, d, 0,0,0);
            d = MFMA16(wv[mt*2+1], xo1, d, 0,0,0);
            *reinterpret_cast<ushort4*>(ovb + vbase + mt*16 + quad*4) = pack4(d, 1.0f);
        }
    }
}

// ---------------------------------------------------------------------------
// K2: Z[q] = sum_{l<q} exp(e[q,l]/32), LDS-staged mini-GEMM.
// v2: 128-q blocks (512 blocks) -- each staged 8KB okb strip now feeds
// 2 output halves (16 MFMA-pairs vs 8), halving total staging traffic and
// per-strip barrier count. A-frag ds_reads hoisted (sub outer, half inner).
// Half h behaves like the old 64-row tile with qt_h = 2*qt2 + h.
// ---------------------------------------------------------------------------
__global__ __launch_bounds__(256) void zrow_part(
    const unsigned short* __restrict__ qb, const unsigned short* __restrict__ okb,
    float* __restrict__ Zbuf)
{
    __shared__ unsigned short slds[2][64 * 64];   // 2 x 8KB staged okb strips

    const int bid = blockIdx.x;       // 0..511
    const int nh = bid & 31;
    const int qt2 = 15 - (bid >> 5);  // longest (32 strips) first
    const int t = threadIdx.x;
    const int w = t >> 6;
    const int lane = t & 63;
    const int n = lane & 15;
    const int quad = lane >> 4;
    const size_t base = (size_t)nh * (LL * 64);
    const size_t nhL = (size_t)nh * LL;

    // held B-frags: qb rows q = qt2*128 + h*64 + w*16 + n
    bf16x8 bq[2][2];
#pragma unroll
    for (int h = 0; h < 2; ++h) {
        const unsigned short* bp = qb + base
            + (size_t)(qt2*128 + h*64 + w*16 + n) * 64 + quad * 8;
        bq[h][0] = ldfrag(bp); bq[h][1] = ldfrag(bp + 32);
    }

    // staging: thread t -> strip-rows srow, srow+32; source chunk pre-swizzled
    const int srow = t >> 3;                        // 0..31
    const int schunk = (t & 7) ^ (srow & 7);        // inverse of read swizzle
    const int soff = srow * 64 + schunk * 8;
    const int nst = 2 * qt2 + 2;

    {   // prologue: stage strip 0 (l in [0,64))
        const unsigned short* s0 = okb + base + soff;
        gload16(s0, &slds[0][t * 8]);
        gload16(s0 + 32 * 64, &slds[0][2048 + t * 8]);
    }
    __syncthreads();

    const int rs0 = (quad ^ (n & 7)) * 8;           // swizzled read offsets
    const int rs1 = ((quad + 4) ^ (n & 7)) * 8;

    float zacc[2] = {0.f, 0.f};
    int buf = 0;
    for (int si = 0; si < nst; ++si) {
        if (si + 1 < nst) {                         // stage next strip first
            const unsigned short* s0 = okb + base + (size_t)((si + 1) * 64) * 64 + soff;
            gload16(s0, &slds[buf ^ 1][t * 8]);
            gload16(s0 + 32 * 64, &slds[buf ^ 1][2048 + t * 8]);
        }
        const unsigned short* S = &slds[buf][0];
#pragma unroll
        for (int sub = 0; sub < 4; ++sub) {
            const int row = sub * 16 + n;
            const bf16x8 a0 = ldfrag(S + row * 64 + rs0);
            const bf16x8 a1 = ldfrag(S + row * 64 + rs1);
#pragma unroll
            for (int h = 0; h < 2; ++h) {
                const int qt_h = 2 * qt2 + h;
                if (si > qt_h) continue;            // l > q entirely (half)
                const bool dstrip = (si == qt_h);
                if (dstrip && sub > w) continue;    // l > q entirely (sub)
                f32x4 d = {0.f, 0.f, 0.f, 0.f};
                d = MFMA16(a0, bq[h][0], d, 0, 0, 0);
                d = MFMA16(a1, bq[h][1], d, 0, 0, 0);
                if (dstrip && sub == w) {           // diagonal: keep l < q
#pragma unroll
                    for (int r = 0; r < 4; ++r)
                        if (quad * 4 + r < n) zacc[h] += EXP2(d[r]);
                } else {
#pragma unroll
                    for (int r = 0; r < 4; ++r) zacc[h] += EXP2(d[r]);
                }
            }
        }
        __syncthreads();                            // next buf staged; reads done
        buf ^= 1;
    }

#pragma unroll
    for (int h = 0; h < 2; ++h) {
        float z = zacc[h];
        z += __shfl_down(z, 32);
        z += __shfl_down(z, 16);
        if (lane < 16)
            Zbuf[nhL + qt2 * 128 + h * 64 + w * 16 + lane] = z;   // plain store
    }
}

// ---------------------------------------------------------------------------
// K3: colsum[l] = sum_{q>l} exp(e[q,l]/32) / Z_full[q].
// v2: 128-l blocks (512 blocks), same halved-staging structure as zrow.
// iz folded into the MFMA ACC INIT: lg2iz[q] = -log2(Z+de) staged in LDS;
// d_init = lg2iz -> exp2(d) == exp(e/32)*iz (kills per-tile multiplies and
// the reciprocal). Half h: l-tile index 2*lt2+h; strip si: q-tile 2*lt2+si;
// skip si<h, diag si==h.
// ---------------------------------------------------------------------------
__global__ __launch_bounds__(256) void colsum_part(
    const unsigned short* __restrict__ qb, const unsigned short* __restrict__ okb,
    const float* __restrict__ Zbuf, const float* __restrict__ ediag,
    float* __restrict__ colsum)
{
    __shared__ unsigned short slds[2][64 * 64];   // 2 x 8KB staged qb strips
    __shared__ __align__(16) float izlds[2][64];  // lg2iz per strip

    const int bid = blockIdx.x;       // 0..511
    const int nh = bid & 31;
    const int lt2 = bid >> 5;         // lt2=0 (32 strips) first
    const int t = threadIdx.x;
    const int w = t >> 6;
    const int lane = t & 63;
    const int n = lane & 15;
    const int quad = lane >> 4;
    const size_t base = (size_t)nh * (LL * 64);
    const size_t nhL = (size_t)nh * LL;

    // held B-frags: okb rows l = lt2*128 + h*64 + w*16 + n
    bf16x8 bl[2][2];
#pragma unroll
    for (int h = 0; h < 2; ++h) {
        const unsigned short* bp = okb + base
            + (size_t)(lt2*128 + h*64 + w*16 + n) * 64 + quad * 8;
        bl[h][0] = ldfrag(bp); bl[h][1] = ldfrag(bp + 32);
    }

    const int srow = t >> 3;
    const int schunk = (t & 7) ^ (srow & 7);
    const int soff = srow * 64 + schunk * 8;
    const int nst = 32 - 2 * lt2;
    const int q00 = lt2 * 128;                      // strip si q-base = q00+si*64

    {   // prologue: stage strip 0 + its lg2iz
        const unsigned short* s0 = qb + base + (size_t)q00 * 64 + soff;
        gload16(s0, &slds[0][t * 8]);
        gload16(s0 + 32 * 64, &slds[0][2048 + t * 8]);
        if (t < 64) {
            const float z = Zbuf[nhL + q00 + t];
            const float e = ediag[nhL + q00 + t];
            izlds[0][t] = -LOG2(z + EXP2(e * CEXP));
        }
    }
    __syncthreads();

    const int rs0 = (quad ^ (n & 7)) * 8;
    const int rs1 = ((quad + 4) ^ (n & 7)) * 8;

    float cacc[2] = {0.f, 0.f};
    int buf = 0;
    for (int si = 0; si < nst; ++si) {
        if (si + 1 < nst) {
            const int qn = q00 + (si + 1) * 64;
            const unsigned short* s0 = qb + base + (size_t)qn * 64 + soff;
            gload16(s0, &slds[buf ^ 1][t * 8]);
            gload16(s0 + 32 * 64, &slds[buf ^ 1][2048 + t * 8]);
            if (t < 64) {
                const float z = Zbuf[nhL + qn + t];
                const float e = ediag[nhL + qn + t];
                izlds[buf ^ 1][t] = -LOG2(z + EXP2(e * CEXP));
            }
        }
        const unsigned short* S = &slds[buf][0];
#pragma unroll
        for (int sub = 0; sub < 4; ++sub) {
            const int row = sub * 16 + n;
            const bf16x8 a0 = ldfrag(S + row * 64 + rs0);
            const bf16x8 a1 = ldfrag(S + row * 64 + rs1);
            const f32x4 lgv = *reinterpret_cast<const f32x4*>(
                &izlds[buf][sub * 16 + quad * 4]);
#pragma unroll
            for (int h = 0; h < 2; ++h) {
                if (si < h) continue;               // q < l entirely (half)
                const bool dstrip = (si == h);
                if (dstrip && sub < w) continue;    // q < l entirely (sub)
                f32x4 d = lgv;                      // acc init = lg2iz[q]
                d = MFMA16(a0, bl[h][0], d, 0, 0, 0);
                d = MFMA16(a1, bl[h][1], d, 0, 0, 0);
                if (dstrip && sub == w) {           // diagonal: keep q > l
#pragma unroll
                    for (int r = 0; r < 4; ++r)
                        if (quad * 4 + r > n) cacc[h] += EXP2(d[r]);
                } else {
#pragma unroll
                    for (int r = 0; r < 4; ++r) cacc[h] += EXP2(d[r]);
                }
            }
        }
        __syncthreads();
        buf ^= 1;
    }

#pragma unroll
    for (int h = 0; h < 2; ++h) {
        float c = cacc[h];
        c += __shfl_down(c, 32);
        c += __shfl_down(c, 16);
        if (lane < 16)
            colsum[nhL + lt2 * 128 + h * 64 + w * 16 + lane] = c;  // plain store
    }
}

// ---------------------------------------------------------------------------
// K6: out = (diag_s*vb + colsum*ovb) @ fcwb^T + fc_b  -- att fused into the
// GEMM's A-staging; diag_s computed inline from Zbuf+ediag.
// ---------------------------------------------------------------------------
#define LOADA(vS, ovS, zS, eS, csS, k) do {                                \
    vS  = ldfrag(pv  + (k)*32);                                            \
    ovS = ldfrag(pov + (k)*32);                                            \
    zS  = Zbuf  [scbase + ((k)>>1)*LL];                                    \
    eS  = ediag [scbase + ((k)>>1)*LL];                                    \
    csS = colsum[scbase + ((k)>>1)*LL];                                    \
} while (0)

#define CVTWRITE(vS, ovS, zS, eS, csS, dst) do {                           \
    const float de_ = EXP2(eS * CEXP);                                     \
    const float ds_ = de_ * (1.f / (zS + de_));                            \
    u16x8 vu_ = __builtin_bit_cast(u16x8, vS);                             \
    u16x8 ou_ = __builtin_bit_cast(u16x8, ovS);                            \
    u16x8 o_;                                                              \
    _Pragma("unroll")                                                      \
    for (int i_ = 0; i_ < 8; ++i_)                                         \
        o_[i_] = f2bf(ds_ * bf2f(vu_[i_]) + csS * bf2f(ou_[i_]));          \
    *reinterpret_cast<u16x8*>(dst) = o_;                                   \
} while (0)

#define COMPUTE(Abuf, Bbuf) do {                                           \
    bf16x8 af_[4], bf_[2];                                                 \
    _Pragma("unroll")                                                      \
    for (int mt = 0; mt < 4; ++mt)                                         \
        af_[mt] = ldfrag((Abuf) + (wr*64 + mt*16 + n)*32 + quad*8);        \
    _Pragma("unroll")                                                      \
    for (int nt = 0; nt < 2; ++nt)                                         \
        bf_[nt] = ldfrag((Bbuf) + (wc*32 + nt*16 + n)*32 + quad*8);        \
    _Pragma("unroll")                                                      \
    for (int mt = 0; mt < 4; ++mt)                                         \
        _Pragma("unroll")                                                  \
        for (int nt = 0; nt < 2; ++nt)                                     \
            acc[mt][nt] = MFMA16(af_[mt], bf_[nt], acc[mt][nt], 0,0,0);    \
} while (0)

__global__ __launch_bounds__(512) void out_kernel(
    const unsigned short* __restrict__ vb, const unsigned short* __restrict__ ovb,
    const float* __restrict__ Zbuf, const float* __restrict__ ediag,
    const float* __restrict__ colsum,
    const unsigned short* __restrict__ fcwb, const float* __restrict__ fc_b,
    float* __restrict__ out)
{
    __shared__ unsigned short lds[2][2][128 * 32];   // [buf][A/B][row*32+k], 32 KB

    const int bid = blockIdx.x;                      // 0..255
    const int swz = (bid & 7) * 32 + (bid >> 3);     // XCD swizzle (256%8==0)
    const int ct = swz & 7;                          // col tile (128 cols)
    const int rt = swz >> 3;                         // row tile (128 rows)
    const int row0 = rt * 128, col0 = ct * 128;

    const int t = threadIdx.x;
    const int w = t >> 6, lane = t & 63;
    const int n = lane & 15, quad = lane >> 4;
    const int wr = w >> 2, wc = w & 3;               // wave -> 64x32 sub-tile

    // A-staging: thread t covers row row0+(t>>2), k-chunk (t&3)*8 (16B)
    const int arow = row0 + (t >> 2);
    const unsigned short* pv  = vb  + (size_t)arow * DD + (t & 3) * 8;
    const unsigned short* pov = ovb + (size_t)arow * DD + (t & 3) * 8;
    const int scbase = (arow >> 11) * (HH * LL) + (arow & 2047);  // + h*LL
    // B-staging (gload_lds direct, linear)
    const unsigned short* gb = fcwb + (size_t)(col0 + (t >> 2)) * DD + (t & 3) * 8;
    unsigned short* la0 = &lds[0][0][t * 8];
    unsigned short* lb0 = &lds[0][1][t * 8];
    unsigned short* la1 = &lds[1][0][t * 8];
    unsigned short* lb1 = &lds[1][1][t * 8];
    const unsigned short* A0 = &lds[0][0][0];
    const unsigned short* B0 = &lds[0][1][0];
    const unsigned short* A1 = &lds[1][0][0];
    const unsigned short* B1 = &lds[1][1][0];

    f32x4 acc[4][2];
#pragma unroll
    for (int mt = 0; mt < 4; ++mt)
#pragma unroll
        for (int nt = 0; nt < 2; ++nt) acc[mt][nt] = (f32x4){0.f, 0.f, 0.f, 0.f};

    // prologue: A(0)->P, A(1)->Q, B(0)->lds0; write A(0)
    bf16x8 vP, ovP, vQ, ovQ; float zP, eP, csP, zQ, eQ, csQ;
    LOADA(vP, ovP, zP, eP, csP, 0);
    LOADA(vQ, ovQ, zQ, eQ, csQ, 1);
    gload16(gb, lb0);
    CVTWRITE(vP, ovP, zP, eP, csP, la0);
    __syncthreads();

    for (int kt = 0; kt < 32; kt += 2) {
        // even step: read lds0, prep lds1 with A(kt+1)/B(kt+1)
        gload16(gb + (kt + 1) * 32, lb1);
        if (kt + 2 < 32) LOADA(vP, ovP, zP, eP, csP, kt + 2);
        COMPUTE(A0, B0);
        CVTWRITE(vQ, ovQ, zQ, eQ, csQ, la1);
        __syncthreads();
        // odd step: read lds1, prep lds0 with A(kt+2)/B(kt+2)
        if (kt + 2 < 32) {
            gload16(gb + (kt + 2) * 32, lb0);
            if (kt + 3 < 32) LOADA(vQ, ovQ, zQ, eQ, csQ, kt + 3);
        }
        COMPUTE(A1, B1);
        if (kt + 2 < 32) CVTWRITE(vP, ovP, zP, eP, csP, la0);
        __syncthreads();
    }

#pragma unroll
    for (int nt = 0; nt < 2; ++nt) {
        const int col = col0 + wc * 32 + nt * 16 + n;
        const float bias = fc_b[col];
#pragma unroll
        for (int mt = 0; mt < 4; ++mt)
#pragma unroll
            for (int r = 0; r < 4; ++r)
                out[(size_t)(row0 + wr * 64 + mt * 16 + quad * 4 + r) * DD + col]
                    = acc[mt][nt][r] + bias;
    }
}

// ---------------------------------------------------------------------------
extern "C" void kernel_launch(void* const* d_in, const int* in_sizes, int n_in,
                              void* d_out, int out_size, void* d_ws, size_t ws_size,
                              hipStream_t stream) {
    const float* values = (const float*)d_in[0];
    const float* keys   = (const float*)d_in[1];
    const float* query  = (const float*)d_in[2];
    const float* ovals  = (const float*)d_in[3];
    const float* okeys  = (const float*)d_in[4];
    const float* Wv     = (const float*)d_in[5];
    const float* Wk     = (const float*)d_in[6];
    const float* Wq     = (const float*)d_in[7];
    const float* fc_w   = (const float*)d_in[8];
    const float* fc_b   = (const float*)d_in[9];
    // d_in[10]: mask — HIST==L makes it pure causal, handled analytically.
    float* out = (float*)d_out;

    float* ws      = (float*)d_ws;
    float* ediag   = ws;                     // 65536 f32
    float* Zbuf    = ediag + 65536;          // 65536 f32 (plain stores)
    float* colsum  = Zbuf + 65536;           // 65536 f32 (plain stores)
    unsigned short* qb   = (unsigned short*)(colsum + 65536); // [32][2048][64] bf16
    unsigned short* okb  = qb   + 4194304;
    unsigned short* vb   = okb  + 4194304;   // [n][l][1024] bf16
    unsigned short* ovb  = vb   + 4194304;
    unsigned short* fcwb = ovb  + 4194304;   // [1024][1024] bf16
    unsigned short* wfrag = fcwb + 1048576;  // 3*8*64*8 = 12288 bf16 (24 KB)

    prep_kernel<<<dim3(6), 256, 0, stream>>>(Wk, Wq, Wv, wfrag);
    proj_kernel<<<dim3(64, 16, 3), 256, 0, stream>>>(
        values, keys, query, ovals, okeys, wfrag, fc_w, fcwb,
        qb, okb, vb, ovb, ediag);
    zrow_part<<<dim3(512), 256, 0, stream>>>(qb, okb, Zbuf);
    colsum_part<<<dim3(512), 256, 0, stream>>>(qb, okb, Zbuf, ediag, colsum);
    out_kernel<<<dim3(256), 512, 0, stream>>>(vb, ovb, Zbuf, ediag, colsum, fcwb, fc_b, out);
}

// Round 8
// 222.494 us; speedup vs baseline: 1.0627x; 1.0627x over previous
//
#include <hip/hip_runtime.h>

// Problem constants
#define NB 2
#define LL 2048
#define DD 1024
#define HH 16
#define NHH (NB*HH)          // 32 (n,h) pairs
#define LT (LL/64)           // 32 tiles of 64
#define KT16 (LL/16)         // 128 16-col tiles
#define CEXP 0.0450842200277801f   // log2(e)/32 : exp(x/32) == exp2(x*CEXP)

typedef __bf16 bf16x8 __attribute__((ext_vector_type(8)));
typedef unsigned short u16x8 __attribute__((ext_vector_type(8)));
typedef float f32x4 __attribute__((ext_vector_type(4)));

#define MFMA16 __builtin_amdgcn_mfma_f32_16x16x32_bf16
#define EXP2 __builtin_amdgcn_exp2f
#define LOG2 __builtin_amdgcn_logf

__device__ __forceinline__ unsigned short f2bf(float f) {
    unsigned u = __float_as_uint(f);
    return (unsigned short)((u + 0x7fffu + ((u >> 16) & 1u)) >> 16);   // RNE
}
__device__ __forceinline__ float bf2f(unsigned short u) {
    return __uint_as_float(((unsigned)u) << 16);
}
__device__ __forceinline__ bf16x8 ldfrag(const unsigned short* p) {
    return *reinterpret_cast<const bf16x8*>(p);
}
__device__ __forceinline__ bf16x8 cvt8v(float4 a, float4 b) {
    u16x8 u;
    u[0]=f2bf(a.x); u[1]=f2bf(a.y); u[2]=f2bf(a.z); u[3]=f2bf(a.w);
    u[4]=f2bf(b.x); u[5]=f2bf(b.y); u[6]=f2bf(b.z); u[7]=f2bf(b.w);
    return __builtin_bit_cast(bf16x8, u);
}
__device__ __forceinline__ ushort4 pack4(f32x4 d, float sc) {
    ushort4 o;
    o.x = f2bf(d[0]*sc); o.y = f2bf(d[1]*sc); o.z = f2bf(d[2]*sc); o.w = f2bf(d[3]*sc);
    return o;
}
// async global->LDS, 16B per lane; LDS dest must be linear (base + lane*16)
__device__ __forceinline__ void gload16(const unsigned short* g, unsigned short* l) {
    __builtin_amdgcn_global_load_lds(
        (const __attribute__((address_space(1))) unsigned int*)g,
        (__attribute__((address_space(3))) unsigned int*)l, 16, 0, 0);
}

// ---------------------------------------------------------------------------
// K0 (prep): wcvt ONLY (6 blocks) -- fcw cvt lives in proj's grid (z=2).
// ---------------------------------------------------------------------------
__global__ __launch_bounds__(256) void prep_kernel(
    const float* __restrict__ Wk, const float* __restrict__ Wq,
    const float* __restrict__ Wv, unsigned short* __restrict__ wfrag)
{
    const int t = threadIdx.x;
    const int s = blockIdx.x * 256 + t;   // 0..1535
    const int m = s >> 9;
    const int rem = s & 511;
    const int f = rem >> 6;
    const int lane = rem & 63;
    const int n16 = lane & 15, quad = lane >> 4;
    const int mt = f >> 1, half = f & 1;
    const float* W = (m == 0) ? Wk : (m == 1) ? Wq : Wv;
    const float* p = W + (mt*16 + n16)*64 + quad*8 + half*32;
    float4 a = *reinterpret_cast<const float4*>(p);
    float4 b = *reinterpret_cast<const float4*>(p + 4);
    *reinterpret_cast<bf16x8*>(wfrag + (size_t)s * 8) = cvt8v(a, b);
}

// ---------------------------------------------------------------------------
// K1: projections via MFMA, D = W(A) . X^T(B); grid (64,16,3).
// z=0: keys/query/okeys (Wk,Wq) + ediag; z=1: values/ovals (Wv);
// z=2: fc_w fp32 -> bf16 (independent slice, hides under latency-bound proj).
// ---------------------------------------------------------------------------
__global__ __launch_bounds__(256) void proj_kernel(
    const float* __restrict__ values, const float* __restrict__ keys,
    const float* __restrict__ query,  const float* __restrict__ ovals,
    const float* __restrict__ okeys,  const unsigned short* __restrict__ wfrag,
    const float* __restrict__ fc_w,   unsigned short* __restrict__ fcwb,
    unsigned short* __restrict__ qb, unsigned short* __restrict__ okb,
    unsigned short* __restrict__ vb, unsigned short* __restrict__ ovb,
    float* __restrict__ ediag)
{
    const int t = threadIdx.x;
    if (blockIdx.z == 2) {
        const int id = blockIdx.y * 64 + blockIdx.x;       // 0..1023
        const int idx = id * 1024 + t * 4;
        float4 wv = *reinterpret_cast<const float4*>(fc_w + idx);
        ushort4 o;
        o.x = f2bf(wv.x); o.y = f2bf(wv.y); o.z = f2bf(wv.z); o.w = f2bf(wv.w);
        *reinterpret_cast<ushort4*>(fcwb + idx) = o;
        return;
    }
    const int w = t >> 6;
    const int lane = t & 63;
    const int n16 = lane & 15;
    const int quad = lane >> 4;
    const int h = blockIdx.y;
    const int row = blockIdx.x * 64 + w * 16 + n16;  // (n*L+l) == this lane's C-col
    const int nn = row >> 11;
    const int ll = row & 2047;
    const size_t xoff  = (size_t)row * DD + h * 64 + quad * 8;       // B-frag src
    const size_t qbase = (((size_t)(nn * HH + h)) * LL + ll) * 64;   // [nh][l][64]
    const size_t vbase = (size_t)row * DD + h * 64;                  // [row][1024]

    if (blockIdx.z == 0) {
        // ---- issue ALL loads first (independent) ----
        const float4* kp = reinterpret_cast<const float4*>(keys  + xoff);
        const float4* qp = reinterpret_cast<const float4*>(query + xoff);
        const float4* op = reinterpret_cast<const float4*>(okeys + xoff);
        float4 k0 = kp[0], k1 = kp[1], k2 = kp[8], k3 = kp[9];   // +0,+4,+32,+36
        float4 q0 = qp[0], q1 = qp[1], q2 = qp[8], q3 = qp[9];
        float4 o0 = op[0], o1 = op[1], o2 = op[8], o3 = op[9];
        bf16x8 wk[8], wq[8];
#pragma unroll
        for (int f = 0; f < 8; ++f) {
            wk[f] = ldfrag(wfrag + (size_t)(f * 64 + lane) * 8);
            wq[f] = ldfrag(wfrag + (size_t)((8 + f) * 64 + lane) * 8);
        }
        // ---- convert ----
        bf16x8 xk0 = cvt8v(k0, k1), xk1 = cvt8v(k2, k3);
        bf16x8 xq0 = cvt8v(q0, q1), xq1 = cvt8v(q2, q3);
        bf16x8 xo0 = cvt8v(o0, o1), xo1 = cvt8v(o2, o3);
        // ---- MFMA ----
        f32x4 ka[4], qa[4];
#pragma unroll
        for (int mt = 0; mt < 4; ++mt) {
            f32x4 d = {0.f,0.f,0.f,0.f};
            d = MFMA16(wk[mt*2], xk0, d, 0,0,0);
            ka[mt] = MFMA16(wk[mt*2+1], xk1, d, 0,0,0);
        }
#pragma unroll
        for (int mt = 0; mt < 4; ++mt) {
            f32x4 d = {0.f,0.f,0.f,0.f};
            d = MFMA16(wq[mt*2], xq0, d, 0,0,0);
            qa[mt] = MFMA16(wq[mt*2+1], xq1, d, 0,0,0);
            *reinterpret_cast<ushort4*>(qb + qbase + mt*16 + quad*4) = pack4(qa[mt], CEXP);
        }
#pragma unroll
        for (int mt = 0; mt < 4; ++mt) {
            f32x4 d = {0.f,0.f,0.f,0.f};
            d = MFMA16(wk[mt*2], xo0, d, 0,0,0);
            d = MFMA16(wk[mt*2+1], xo1, d, 0,0,0);
            *reinterpret_cast<ushort4*>(okb + qbase + mt*16 + quad*4) = pack4(d, 1.0f);
        }
        // ediag[l] = sum_d q*k (fp32)
        float p = 0.f;
#pragma unroll
        for (int mt = 0; mt < 4; ++mt)
            p += qa[mt][0]*ka[mt][0] + qa[mt][1]*ka[mt][1]
               + qa[mt][2]*ka[mt][2] + qa[mt][3]*ka[mt][3];
        p += __shfl_xor(p, 16);
        p += __shfl_xor(p, 32);
        if (lane < 16)
            ediag[((size_t)(nn * HH + h)) * LL + ll] = p;
    } else {
        const float4* vp = reinterpret_cast<const float4*>(values + xoff);
        const float4* op = reinterpret_cast<const float4*>(ovals  + xoff);
        float4 v0 = vp[0], v1 = vp[1], v2 = vp[8], v3 = vp[9];
        float4 o0 = op[0], o1 = op[1], o2 = op[8], o3 = op[9];
        bf16x8 wv[8];
#pragma unroll
        for (int f = 0; f < 8; ++f)
            wv[f] = ldfrag(wfrag + (size_t)((16 + f) * 64 + lane) * 8);
        bf16x8 xv0 = cvt8v(v0, v1), xv1 = cvt8v(v2, v3);
        bf16x8 xo0 = cvt8v(o0, o1), xo1 = cvt8v(o2, o3);
#pragma unroll
        for (int mt = 0; mt < 4; ++mt) {
            f32x4 d = {0.f,0.f,0.f,0.f};
            d = MFMA16(wv[mt*2], xv0, d, 0,0,0);
            d = MFMA16(wv[mt*2+1], xv1, d, 0,0,0);
            *reinterpret_cast<ushort4*>(vb + vbase + mt*16 + quad*4) = pack4(d, 1.0f);
        }
#pragma unroll
        for (int mt = 0; mt < 4; ++mt) {
            f32x4 d = {0.f,0.f,0.f,0.f};
            d = MFMA16(wv[mt*2], xo0, d, 0,0,0);
            d = MFMA16(wv[mt*2+1], xo1, d, 0,0,0);
            *reinterpret_cast<ushort4*>(ovb + vbase + mt*16 + quad*4) = pack4(d, 1.0f);
        }
    }
}

// ---------------------------------------------------------------------------
// K2: Z[q] = sum_{l<q} exp(e[q,l]/32), LDS-staged mini-GEMM.
// REVERTED to the verified R5 64-q/1024-block form: R6's 128-row tiling
// doubled the longest block's serial work (32 strips x 16 MFMA-pairs vs x8)
// and halved occupancy -- tail-bound regression (+14us). Small blocks ARE
// the load balancer for triangular work.
// ---------------------------------------------------------------------------
__global__ __launch_bounds__(256) void zrow_part(
    const unsigned short* __restrict__ qb, const unsigned short* __restrict__ okb,
    float* __restrict__ Zbuf)
{
    __shared__ unsigned short slds[2][64 * 64];   // 2 x 8KB staged okb strips

    const int bid = blockIdx.x;       // 0..1023
    const int nh = bid & 31;
    const int qt = 31 - (bid >> 5);   // longest (32 strips) first
    const int t = threadIdx.x;
    const int w = t >> 6;
    const int lane = t & 63;
    const int n = lane & 15;
    const int quad = lane >> 4;
    const size_t base = (size_t)nh * (LL * 64);
    const size_t nhL = (size_t)nh * LL;

    // held B-frags: qb rows q = qt*64 + w*16 + n
    const unsigned short* bp = qb + base + (size_t)(qt*64 + w*16 + n) * 64 + quad * 8;
    const bf16x8 bq0 = ldfrag(bp);
    const bf16x8 bq1 = ldfrag(bp + 32);

    // staging: thread t -> strip-rows srow, srow+32; source chunk pre-swizzled
    const int srow = t >> 3;                        // 0..31
    const int schunk = (t & 7) ^ (srow & 7);        // inverse of read swizzle
    const int soff = srow * 64 + schunk * 8;
    const int nst = qt + 1;

    {   // prologue: stage strip 0 (l in [0,64))
        const unsigned short* s0 = okb + base + soff;
        gload16(s0, &slds[0][t * 8]);
        gload16(s0 + 32 * 64, &slds[0][2048 + t * 8]);
    }
    __syncthreads();

    const int rs0 = (quad ^ (n & 7)) * 8;           // swizzled read offsets
    const int rs1 = ((quad + 4) ^ (n & 7)) * 8;

    float zacc = 0.f;
    int buf = 0;
    for (int si = 0; si < nst; ++si) {
        if (si + 1 < nst) {                         // stage next strip first
            const unsigned short* s0 = okb + base + (size_t)((si + 1) * 64) * 64 + soff;
            gload16(s0, &slds[buf ^ 1][t * 8]);
            gload16(s0 + 32 * 64, &slds[buf ^ 1][2048 + t * 8]);
        }
        const unsigned short* S = &slds[buf][0];
        const bool dstrip = (si == qt);             // strip containing l == q
#pragma unroll
        for (int sub = 0; sub < 4; ++sub) {
            if (dstrip && sub > w) continue;        // l > q entirely
            const int row = sub * 16 + n;
            const bf16x8 a0 = ldfrag(S + row * 64 + rs0);
            const bf16x8 a1 = ldfrag(S + row * 64 + rs1);
            f32x4 d = {0.f, 0.f, 0.f, 0.f};
            d = MFMA16(a0, bq0, d, 0, 0, 0);
            d = MFMA16(a1, bq1, d, 0, 0, 0);
            if (dstrip && sub == w) {               // diagonal: keep l < q
#pragma unroll
                for (int r = 0; r < 4; ++r)
                    if (quad * 4 + r < n) zacc += EXP2(d[r]);
            } else {
#pragma unroll
                for (int r = 0; r < 4; ++r) zacc += EXP2(d[r]);
            }
        }
        __syncthreads();                            // next buf staged; reads done
        buf ^= 1;
    }

    zacc += __shfl_down(zacc, 32);
    zacc += __shfl_down(zacc, 16);
    if (lane < 16)
        Zbuf[nhL + qt * 64 + w * 16 + lane] = zacc;   // plain store, single owner
}

// ---------------------------------------------------------------------------
// K3: colsum[l] = sum_{q>l} exp(e[q,l]/32) / Z_full[q].
// R5 64-l/1024-block form (reverted tiling) + KEPT lg2iz acc-init:
// lg2iz[q] = -log2(Z+de) staged in LDS; d_init = lg2iz so exp2(d) ==
// exp(e/32)*iz -- kills the per-tile iz multiplies and in-loop rcp.
// ---------------------------------------------------------------------------
__global__ __launch_bounds__(256) void colsum_part(
    const unsigned short* __restrict__ qb, const unsigned short* __restrict__ okb,
    const float* __restrict__ Zbuf, const float* __restrict__ ediag,
    float* __restrict__ colsum)
{
    __shared__ unsigned short slds[2][64 * 64];   // 2 x 8KB staged qb strips
    __shared__ __align__(16) float izlds[2][64];  // lg2iz per strip

    const int bid = blockIdx.x;       // 0..1023
    const int nh = bid & 31;
    const int lt = bid >> 5;          // lt=0 (32 strips) first
    const int t = threadIdx.x;
    const int w = t >> 6;
    const int lane = t & 63;
    const int n = lane & 15;
    const int quad = lane >> 4;
    const size_t base = (size_t)nh * (LL * 64);
    const size_t nhL = (size_t)nh * LL;

    // held B-frags: okb rows l = lt*64 + w*16 + n
    const unsigned short* bp = okb + base + (size_t)(lt*64 + w*16 + n) * 64 + quad * 8;
    const bf16x8 bl0 = ldfrag(bp);
    const bf16x8 bl1 = ldfrag(bp + 32);

    const int srow = t >> 3;
    const int schunk = (t & 7) ^ (srow & 7);
    const int soff = srow * 64 + schunk * 8;
    const int nst = 32 - lt;
    const int q00 = lt * 64;                        // strip si q-base = q00+si*64

    {   // prologue: stage strip 0 + its lg2iz
        const unsigned short* s0 = qb + base + (size_t)q00 * 64 + soff;
        gload16(s0, &slds[0][t * 8]);
        gload16(s0 + 32 * 64, &slds[0][2048 + t * 8]);
        if (t < 64) {
            const float z = Zbuf[nhL + q00 + t];
            const float e = ediag[nhL + q00 + t];
            izlds[0][t] = -LOG2(z + EXP2(e * CEXP));
        }
    }
    __syncthreads();

    const int rs0 = (quad ^ (n & 7)) * 8;
    const int rs1 = ((quad + 4) ^ (n & 7)) * 8;

    float cacc = 0.f;
    int buf = 0;
    for (int si = 0; si < nst; ++si) {
        if (si + 1 < nst) {
            const int qn = q00 + (si + 1) * 64;
            const unsigned short* s0 = qb + base + (size_t)qn * 64 + soff;
            gload16(s0, &slds[buf ^ 1][t * 8]);
            gload16(s0 + 32 * 64, &slds[buf ^ 1][2048 + t * 8]);
            if (t < 64) {
                const float z = Zbuf[nhL + qn + t];
                const float e = ediag[nhL + qn + t];
                izlds[buf ^ 1][t] = -LOG2(z + EXP2(e * CEXP));
            }
        }
        const unsigned short* S = &slds[buf][0];
        const bool dstrip = (si == 0);              // strip containing q == l
#pragma unroll
        for (int sub = 0; sub < 4; ++sub) {
            if (dstrip && sub < w) continue;        // q < l entirely
            const int row = sub * 16 + n;
            const bf16x8 a0 = ldfrag(S + row * 64 + rs0);
            const bf16x8 a1 = ldfrag(S + row * 64 + rs1);
            const f32x4 lgv = *reinterpret_cast<const f32x4*>(
                &izlds[buf][sub * 16 + quad * 4]);
            f32x4 d = lgv;                          // acc init = lg2iz[q]
            d = MFMA16(a0, bl0, d, 0, 0, 0);
            d = MFMA16(a1, bl1, d, 0, 0, 0);
            if (dstrip && sub == w) {               // diagonal: keep q > l
#pragma unroll
                for (int r = 0; r < 4; ++r)
                    if (quad * 4 + r > n) cacc += EXP2(d[r]);
            } else {
#pragma unroll
                for (int r = 0; r < 4; ++r) cacc += EXP2(d[r]);
            }
        }
        __syncthreads();
        buf ^= 1;
    }

    cacc += __shfl_down(cacc, 32);
    cacc += __shfl_down(cacc, 16);
    if (lane < 16)
        colsum[nhL + lt * 64 + w * 16 + lane] = cacc;  // plain store
}

// ---------------------------------------------------------------------------
// K6: out = (diag_s*vb + colsum*ovb) @ fcwb^T + fc_b  -- att fused into the
// GEMM's A-staging; diag_s computed inline from Zbuf+ediag.
// ---------------------------------------------------------------------------
#define LOADA(vS, ovS, zS, eS, csS, k) do {                                \
    vS  = ldfrag(pv  + (k)*32);                                            \
    ovS = ldfrag(pov + (k)*32);                                            \
    zS  = Zbuf  [scbase + ((k)>>1)*LL];                                    \
    eS  = ediag [scbase + ((k)>>1)*LL];                                    \
    csS = colsum[scbase + ((k)>>1)*LL];                                    \
} while (0)

#define CVTWRITE(vS, ovS, zS, eS, csS, dst) do {                           \
    const float de_ = EXP2(eS * CEXP);                                     \
    const float ds_ = de_ * (1.f / (zS + de_));                            \
    u16x8 vu_ = __builtin_bit_cast(u16x8, vS);                             \
    u16x8 ou_ = __builtin_bit_cast(u16x8, ovS);                            \
    u16x8 o_;                                                              \
    _Pragma("unroll")                                                      \
    for (int i_ = 0; i_ < 8; ++i_)                                         \
        o_[i_] = f2bf(ds_ * bf2f(vu_[i_]) + csS * bf2f(ou_[i_]));          \
    *reinterpret_cast<u16x8*>(dst) = o_;                                   \
} while (0)

#define COMPUTE(Abuf, Bbuf) do {                                           \
    bf16x8 af_[4], bf_[2];                                                 \
    _Pragma("unroll")                                                      \
    for (int mt = 0; mt < 4; ++mt)                                         \
        af_[mt] = ldfrag((Abuf) + (wr*64 + mt*16 + n)*32 + quad*8);        \
    _Pragma("unroll")                                                      \
    for (int nt = 0; nt < 2; ++nt)                                         \
        bf_[nt] = ldfrag((Bbuf) + (wc*32 + nt*16 + n)*32 + quad*8);        \
    _Pragma("unroll")                                                      \
    for (int mt = 0; mt < 4; ++mt)                                         \
        _Pragma("unroll")                                                  \
        for (int nt = 0; nt < 2; ++nt)                                     \
            acc[mt][nt] = MFMA16(af_[mt], bf_[nt], acc[mt][nt], 0,0,0);    \
} while (0)

__global__ __launch_bounds__(512) void out_kernel(
    const unsigned short* __restrict__ vb, const unsigned short* __restrict__ ovb,
    const float* __restrict__ Zbuf, const float* __restrict__ ediag,
    const float* __restrict__ colsum,
    const unsigned short* __restrict__ fcwb, const float* __restrict__ fc_b,
    float* __restrict__ out)
{
    __shared__ unsigned short lds[2][2][128 * 32];   // [buf][A/B][row*32+k], 32 KB

    const int bid = blockIdx.x;                      // 0..255
    const int swz = (bid & 7) * 32 + (bid >> 3);     // XCD swizzle (256%8==0)
    const int ct = swz & 7;                          // col tile (128 cols)
    const int rt = swz >> 3;                         // row tile (128 rows)
    const int row0 = rt * 128, col0 = ct * 128;

    const int t = threadIdx.x;
    const int w = t >> 6, lane = t & 63;
    const int n = lane & 15, quad = lane >> 4;
    const int wr = w >> 2, wc = w & 3;               // wave -> 64x32 sub-tile

    // A-staging: thread t covers row row0+(t>>2), k-chunk (t&3)*8 (16B)
    const int arow = row0 + (t >> 2);
    const unsigned short* pv  = vb  + (size_t)arow * DD + (t & 3) * 8;
    const unsigned short* pov = ovb + (size_t)arow * DD + (t & 3) * 8;
    const int scbase = (arow >> 11) * (HH * LL) + (arow & 2047);  // + h*LL
    // B-staging (gload_lds direct, linear)
    const unsigned short* gb = fcwb + (size_t)(col0 + (t >> 2)) * DD + (t & 3) * 8;
    unsigned short* la0 = &lds[0][0][t * 8];
    unsigned short* lb0 = &lds[0][1][t * 8];
    unsigned short* la1 = &lds[1][0][t * 8];
    unsigned short* lb1 = &lds[1][1][t * 8];
    const unsigned short* A0 = &lds[0][0][0];
    const unsigned short* B0 = &lds[0][1][0];
    const unsigned short* A1 = &lds[1][0][0];
    const unsigned short* B1 = &lds[1][1][0];

    f32x4 acc[4][2];
#pragma unroll
    for (int mt = 0; mt < 4; ++mt)
#pragma unroll
        for (int nt = 0; nt < 2; ++nt) acc[mt][nt] = (f32x4){0.f, 0.f, 0.f, 0.f};

    // prologue: A(0)->P, A(1)->Q, B(0)->lds0; write A(0)
    bf16x8 vP, ovP, vQ, ovQ; float zP, eP, csP, zQ, eQ, csQ;
    LOADA(vP, ovP, zP, eP, csP, 0);
    LOADA(vQ, ovQ, zQ, eQ, csQ, 1);
    gload16(gb, lb0);
    CVTWRITE(vP, ovP, zP, eP, csP, la0);
    __syncthreads();

    for (int kt = 0; kt < 32; kt += 2) {
        // even step: read lds0, prep lds1 with A(kt+1)/B(kt+1)
        gload16(gb + (kt + 1) * 32, lb1);
        if (kt + 2 < 32) LOADA(vP, ovP, zP, eP, csP, kt + 2);
        COMPUTE(A0, B0);
        CVTWRITE(vQ, ovQ, zQ, eQ, csQ, la1);
        __syncthreads();
        // odd step: read lds1, prep lds0 with A(kt+2)/B(kt+2)
        if (kt + 2 < 32) {
            gload16(gb + (kt + 2) * 32, lb0);
            if (kt + 3 < 32) LOADA(vQ, ovQ, zQ, eQ, csQ, kt + 3);
        }
        COMPUTE(A1, B1);
        if (kt + 2 < 32) CVTWRITE(vP, ovP, zP, eP, csP, la0);
        __syncthreads();
    }

#pragma unroll
    for (int nt = 0; nt < 2; ++nt) {
        const int col = col0 + wc * 32 + nt * 16 + n;
        const float bias = fc_b[col];
#pragma unroll
        for (int mt = 0; mt < 4; ++mt)
#pragma unroll
            for (int r = 0; r < 4; ++r)
                out[(size_t)(row0 + wr * 64 + mt * 16 + quad * 4 + r) * DD + col]
                    = acc[mt][nt][r] + bias;
    }
}

// ---------------------------------------------------------------------------
extern "C" void kernel_launch(void* const* d_in, const int* in_sizes, int n_in,
                              void* d_out, int out_size, void* d_ws, size_t ws_size,
                              hipStream_t stream) {
    const float* values = (const float*)d_in[0];
    const float* keys   = (const float*)d_in[1];
    const float* query  = (const float*)d_in[2];
    const float* ovals  = (const float*)d_in[3];
    const float* okeys  = (const float*)d_in[4];
    const float* Wv     = (const float*)d_in[5];
    const float* Wk     = (const float*)d_in[6];
    const float* Wq     = (const float*)d_in[7];
    const float* fc_w   = (const float*)d_in[8];
    const float* fc_b   = (const float*)d_in[9];
    // d_in[10]: mask — HIST==L makes it pure causal, handled analytically.
    float* out = (float*)d_out;

    float* ws      = (float*)d_ws;
    float* ediag   = ws;                     // 65536 f32
    float* Zbuf    = ediag + 65536;          // 65536 f32 (plain stores)
    float* colsum  = Zbuf + 65536;           // 65536 f32 (plain stores)
    unsigned short* qb   = (unsigned short*)(colsum + 65536); // [32][2048][64] bf16
    unsigned short* okb  = qb   + 4194304;
    unsigned short* vb   = okb  + 4194304;   // [n][l][1024] bf16
    unsigned short* ovb  = vb   + 4194304;
    unsigned short* fcwb = ovb  + 4194304;   // [1024][1024] bf16
    unsigned short* wfrag = fcwb + 1048576;  // 3*8*64*8 = 12288 bf16 (24 KB)

    prep_kernel<<<dim3(6), 256, 0, stream>>>(Wk, Wq, Wv, wfrag);
    proj_kernel<<<dim3(64, 16, 3), 256, 0, stream>>>(
        values, keys, query, ovals, okeys, wfrag, fc_w, fcwb,
        qb, okb, vb, ovb, ediag);
    zrow_part<<<dim3(1024), 256, 0, stream>>>(qb, okb, Zbuf);
    colsum_part<<<dim3(1024), 256, 0, stream>>>(qb, okb, Zbuf, ediag, colsum);
    out_kernel<<<dim3(256), 512, 0, stream>>>(vb, ovb, Zbuf, ediag, colsum, fcwb, fc_b, out);
}